// Round 10
// baseline (749.634 us; speedup 1.0000x reference)
//
#include <hip/hip_runtime.h>
#include <hip/hip_bf16.h>
#include <math.h>

// B=4, S=2048, E=2048, H=16, D=128. Inputs/outputs FP32; internal bf16 MFMA, f32 acc.

typedef __bf16 bf16_t;
typedef __bf16 bf16x2 __attribute__((ext_vector_type(2)));
typedef __bf16 bf16x4 __attribute__((ext_vector_type(4)));
typedef __bf16 bf16x8 __attribute__((ext_vector_type(8)));
typedef float f32x2 __attribute__((ext_vector_type(2)));
typedef float f32x4 __attribute__((ext_vector_type(4)));
typedef float f32x16 __attribute__((ext_vector_type(16)));
typedef unsigned int u32;
typedef u32 u32x4 __attribute__((ext_vector_type(4)));

typedef __attribute__((address_space(1))) const void gas_cvoid;
typedef __attribute__((address_space(3))) void las_void;

#define MFMA16(a, b, c) __builtin_amdgcn_mfma_f32_16x16x32_bf16((a), (b), (c), 0, 0, 0)
#define MFMA32(a, b, c) __builtin_amdgcn_mfma_f32_32x32x16_bf16((a), (b), (c), 0, 0, 0)

__device__ __forceinline__ void gload16(const void* g, void* l) {
  __builtin_amdgcn_global_load_lds((gas_cvoid*)g, (las_void*)l, 16, 0, 0);
}
// lane[i] <-> lane[i+32] pairwise exchange of two regs (T12 primitive, m255)
__device__ __forceinline__ void pl32(u32& a, u32& b) {
  asm volatile("v_permlane32_swap_b32 %0, %1" : "+v"(a), "+v"(b));
}
// bare v_exp_f32 (D = 2^S0); exp2f() is OCML w/ fixup, __exp2f doesn't exist.
__device__ __forceinline__ float fexp2(float x) {
  float r;
  asm("v_exp_f32 %0, %1" : "=v"(r) : "v"(x));
  return r;
}

// ---------------------------------------------------------------------------
// f32 -> bf16 elementwise, 4 elems/thread.
// ---------------------------------------------------------------------------
__global__ __launch_bounds__(256) void cvt_bf16(const float* __restrict__ in,
                                                bf16_t* __restrict__ out) {
  const size_t i = ((size_t)blockIdx.x * 256 + threadIdx.x) * 4;
  f32x4 v = *(const f32x4*)&in[i];
  bf16x4 o;
#pragma unroll
  for (int j = 0; j < 4; ++j) o[j] = (bf16_t)v[j];
  *(bf16x4*)&out[i] = o;
}
// 4 weight matrices in one launch: 4096 blocks per tensor.
__global__ __launch_bounds__(256) void cvt_w4(const float* __restrict__ w0,
                                              const float* __restrict__ w1,
                                              const float* __restrict__ w2,
                                              const float* __restrict__ w3,
                                              bf16_t* __restrict__ o0,
                                              bf16_t* __restrict__ o1,
                                              bf16_t* __restrict__ o2,
                                              bf16_t* __restrict__ o3) {
  const int which = blockIdx.x >> 12;
  const float* in = which == 0 ? w0 : which == 1 ? w1 : which == 2 ? w2 : w3;
  bf16_t* out = which == 0 ? o0 : which == 1 ? o1 : which == 2 ? o2 : o3;
  const size_t i = ((size_t)(blockIdx.x & 4095) * 256 + threadIdx.x) * 4;
  f32x4 v = *(const f32x4*)&in[i];
  bf16x4 o;
#pragma unroll
  for (int j = 0; j < 4; ++j) o[j] = (bf16_t)v[j];
  *(bf16x4*)&out[i] = o;
}

// ---------------------------------------------------------------------------
// 8-phase NT GEMM with COUNTED vmcnt (T4): C[M][N] = A[M][2048] @ Bt[N][2048]^T.
// 256x256 tile, BK=64, 512 thr / 8 waves (2M x 4N), LDS 128 KiB dbuf.
// (unchanged -- verified since round 5)
// ---------------------------------------------------------------------------
template <int MODE, typename CT, int NT_T>
__global__ __launch_bounds__(512, 2) void gemm8(const bf16_t* __restrict__ A,
                                                const bf16_t* __restrict__ Bt,
                                                CT* __restrict__ C) {
  constexpr int K = 2048;
  __shared__ __attribute__((aligned(16))) char lds[131072];
  const int tid = threadIdx.x;
  const int wave = tid >> 6, lane = tid & 63;
  const int bid = blockIdx.x;
  const int swz = (bid & 7) * 32 + (bid >> 3);  // grid 256, bijective XCD swizzle
  const int m0 = (swz / NT_T) * 256, n0 = (swz % NT_T) * 256;

  const int srow = tid >> 3;
  const int scol = ((tid & 7) ^ (srow & 7)) * 8;
  const bf16_t* aBase = A + (size_t)(m0 + srow) * K + scol;
  const bf16_t* bBase = Bt + (size_t)(n0 + srow) * K + scol;

  const int wm = wave >> 2, wn = wave & 3;
  const int l15 = lane & 15, l4 = lane >> 4;
  const int axor = l15 & 7;
  char* const wdst = lds + wave * 1024;

  f32x4 acc[8][4] = {};

  // prologue: tile 0 into buf 0, canonical order
  gload16(bBase, wdst + 32768);
  gload16(bBase + (size_t)64 * K, wdst + 32768 + 8192);
  gload16(bBase + (size_t)128 * K, wdst + 32768 + 16384);
  gload16(bBase + (size_t)192 * K, wdst + 32768 + 24576);
  gload16(aBase, wdst);
  gload16(aBase + (size_t)128 * K, wdst + 16384);
  gload16(aBase + (size_t)64 * K, wdst + 8192);
  gload16(aBase + (size_t)192 * K, wdst + 24576);

  for (int t = 0; t < 32; ++t) {
    const int buf = t & 1, nbuf = buf ^ 1;
    const char* la = lds + buf * 65536 + wm * 16384;
    const char* lb = lds + buf * 65536 + 32768 + (wn >> 1) * 16384 + (wn & 1) * 8192;
    char* const ndst = wdst + nbuf * 65536;
    bf16x8 bF[4][2];
#pragma unroll
    for (int q = 0; q < 4; ++q) {
      if (q == 0) {
        asm volatile("s_waitcnt vmcnt(2)" ::: "memory");
      } else if (q == 2) {
        if (t < 31)
          asm volatile("s_waitcnt vmcnt(4)" ::: "memory");
        else
          asm volatile("s_waitcnt vmcnt(0)" ::: "memory");
      }
      __builtin_amdgcn_s_barrier();

      bf16x8 aF[2][2];
#pragma unroll
      for (int dm = 0; dm < 2; ++dm)
#pragma unroll
        for (int kk = 0; kk < 2; ++kk)
          aF[dm][kk] = *(const bf16x8*)(la + ((q * 2 + dm) * 16 + l15) * 128 +
                                        ((kk * 4 + l4) ^ axor) * 16);
      if (q == 0) {
#pragma unroll
        for (int ni = 0; ni < 4; ++ni)
#pragma unroll
          for (int kk = 0; kk < 2; ++kk)
            bF[ni][kk] = *(const bf16x8*)(lb + (ni * 16 + l15) * 128 +
                                          ((kk * 4 + l4) ^ axor) * 16);
      }
      // stage tile t+1, 2 chunks per phase, canonical order
      if (t < 31) {
        const int off = (t + 1) * 64;
        if (q == 0) {
          gload16(bBase + off, ndst + 32768);
          gload16(bBase + (size_t)64 * K + off, ndst + 32768 + 8192);
        } else if (q == 1) {
          gload16(bBase + (size_t)128 * K + off, ndst + 32768 + 16384);
          gload16(bBase + (size_t)192 * K + off, ndst + 32768 + 24576);
        } else if (q == 2) {
          gload16(aBase + off, ndst);
          gload16(aBase + (size_t)128 * K + off, ndst + 16384);
        } else {
          gload16(aBase + (size_t)64 * K + off, ndst + 8192);
          gload16(aBase + (size_t)192 * K + off, ndst + 24576);
        }
      }
      __builtin_amdgcn_s_setprio(1);
#pragma unroll
      for (int kk = 0; kk < 2; ++kk)
#pragma unroll
        for (int dm = 0; dm < 2; ++dm)
#pragma unroll
          for (int ni = 0; ni < 4; ++ni)
            acc[q * 2 + dm][ni] = MFMA16(aF[dm][kk], bF[ni][kk], acc[q * 2 + dm][ni]);
      __builtin_amdgcn_s_setprio(0);
    }
  }

  const int rBase = m0 + wm * 128 + l4 * 4;
  const int cBase = n0 + wn * 64 + l15;
#pragma unroll
  for (int mi = 0; mi < 8; ++mi)
#pragma unroll
    for (int ni = 0; ni < 4; ++ni)
#pragma unroll
      for (int j = 0; j < 4; ++j) {
        const int r = rBase + mi * 16 + j;
        const int c = cBase + ni * 16;
        const CT v = (CT)acc[mi][ni][j];
        if (MODE == 0) {
          const int b = r >> 11, s = r & 2047, hh = c >> 7, d = c & 127;
          C[(((size_t)(b * 16 + hh)) * 2048 + s) * 128 + d] = v;
        } else if (MODE == 1) {
          C[(size_t)r * 2048 + c] = v;
        } else {  // r = h*128+dd (Wv row), c = b*2048+s
          const int hh = r >> 7, dd = r & 127, b = c >> 11, s = c & 2047;
          C[((size_t)(b * 16 + hh) * 128 + dd) * 2048 + s] = v;
        }
      }
}

// ---------------------------------------------------------------------------
// Fused RoPE + RMSNorm on BOTH Q and K in one dispatch (grid 8192: low half Q,
// high half K). In place on [B*H, S, D=128] bf16.
// ---------------------------------------------------------------------------
__global__ __launch_bounds__(256) void rope_rms2(bf16_t* __restrict__ Qb,
                                                 bf16_t* __restrict__ Kb,
                                                 const float* __restrict__ Cs,
                                                 const float* __restrict__ Sn) {
  bf16_t* T = (blockIdx.x >> 12) ? Kb : Qb;
  const int bid = blockIdx.x & 4095;
  const int wave = threadIdx.x >> 6, lane = threadIdx.x & 63;
#pragma unroll 1
  for (int rr = 0; rr < 8; ++rr) {
    const size_t row = (size_t)bid * 32 + wave * 8 + rr;
    const int s = (int)(row & 2047);
    bf16_t* p = &T[row * 128 + 2 * lane];
    const float a0 = (float)p[0], a1 = (float)p[1];
    f32x2 cv = *(const f32x2*)&Cs[(size_t)s * 128 + 2 * lane];
    f32x2 sv = *(const f32x2*)&Sn[(size_t)s * 128 + 2 * lane];
    const float p0 = __shfl_xor(a0, 32);
    const float p1 = __shfl_xor(a1, 32);
    const float sg = (lane < 32) ? -1.f : 1.f;
    const float r0 = a0 * cv.x + sg * p0 * sv.x;
    const float r1 = a1 * cv.y + sg * p1 * sv.y;
    float ss = r0 * r0 + r1 * r1;
#pragma unroll
    for (int off = 1; off < 64; off <<= 1) ss += __shfl_xor(ss, off);
    const float inv = rsqrtf(ss * (1.0f / 128.0f) + 1e-6f);
    p[0] = (bf16_t)(r0 * inv);
    p[1] = (bf16_t)(r1 * inv);
  }
}

// ---------------------------------------------------------------------------
// Flash attention, 2 q-tiles per wave (static 2-state, rule-#20-safe named
// A/B). Grid 256 (1 block/CU): 64 bh x 4 qb of 512 q-rows; each wave owns
// rows q0..q0+31 (A) and q0+256..q0+287 (B). Each staged K/V tile now feeds
// 2x the MFMAs from the SAME ds_reads (kf/vf shared by A and B) -> LDS
// reads/FLOP and K/V HBM refetch both halve; independent A/B chains give
// within-wave ILP. Static-bound softmax (round-9, verified). Counted-vmcnt
// rotation + r&7 swizzle (round-5, verified).
// ---------------------------------------------------------------------------
__global__ __launch_bounds__(512) void attn_fwd(const bf16_t* __restrict__ Q,
                                                const bf16_t* __restrict__ K,
                                                const bf16_t* __restrict__ Vt,
                                                bf16_t* __restrict__ Y) {
  __shared__ __attribute__((aligned(16))) bf16_t ldsK[2][64 * 128];
  __shared__ __attribute__((aligned(16))) bf16_t ldsV[2][128 * 64];
  const int tid = threadIdx.x, wave = tid >> 6, lane = tid & 63;
  const int l31 = lane & 31, hi = lane >> 5;
  const int pid = blockIdx.x;
  const int bh = (pid & 7) * 8 + ((pid >> 3) & 7);  // same-head qb-blocks share XCD
  const int qb = pid >> 6;                          // 0..3
  const int b = bh >> 4, h = bh & 15;
  const bf16_t* Qh = Q + (size_t)bh * 2048 * 128;
  const bf16_t* Kh = K + (size_t)bh * 2048 * 128;
  const bf16_t* Vh = Vt + (size_t)bh * 128 * 2048;
  const int q0 = qb * 512 + wave * 32;  // tile A; tile B = q0 + 256

  bf16x8 qfA[8], qfB[8];
#pragma unroll
  for (int dk = 0; dk < 8; ++dk) {
    qfA[dk] = *(const bf16x8*)&Qh[(size_t)(q0 + l31) * 128 + dk * 16 + hi * 8];
    qfB[dk] = *(const bf16x8*)&Qh[(size_t)(q0 + 256 + l31) * 128 + dk * 16 + hi * 8];
  }

  f32x16 otA[4] = {}, otB[4] = {};
  float lA = 0.f, lB = 0.f;
  const float SC2 = 0.08838834764831845f * 1.44269504088896341f;  // scale*log2e
  const float NC2 = -11.5f * 1.44269504088896341f;                // -M*log2e

  auto stage = [&](int kt, int bu) {
#pragma unroll
    for (int i = 0; i < 2; ++i) {
      const int G = wave * 64 + lane + i * 512;
      char* dstK = (char*)&ldsK[bu][0] + (wave * 64 + i * 512) * 16;
      char* dstV = (char*)&ldsV[bu][0] + (wave * 64 + i * 512) * 16;
      const int kvr = G >> 4, glk = G & 15;
      gload16(Kh + (size_t)(kt * 64 + kvr) * 128 + ((glk ^ (kvr & 7)) * 8), dstK);
      const int dr = G >> 3, glv = G & 7;
      gload16(Vh + (size_t)dr * 2048 + kt * 64 + ((glv ^ (dr & 7)) * 8), dstV);
    }
  };

  // prologue: tiles 0 and 1 in flight; wait tile 0 only
  stage(0, 0);
  stage(1, 1);
  asm volatile("s_waitcnt vmcnt(4)" ::: "memory");
  __builtin_amdgcn_s_barrier();
  __builtin_amdgcn_sched_barrier(0);

  for (int kt = 0; kt < 32; ++kt) {
    const int bu = kt & 1;
    const int r7 = l31 & 7;

    // ---- S^T = K @ Q^T for both q-tiles; kf reads SHARED (4 MFMA per read-pair)
    f32x16 sa0A = {}, sa1A = {}, sa0B = {}, sa1B = {};
    __builtin_amdgcn_s_setprio(1);
#pragma unroll
    for (int dk = 0; dk < 8; ++dk) {
      const int g = ((dk << 1) | hi) ^ r7;
      bf16x8 kf0 = *(const bf16x8*)&ldsK[bu][l31 * 128 + g * 8];
      bf16x8 kf1 = *(const bf16x8*)&ldsK[bu][(32 + l31) * 128 + g * 8];
      sa0A = MFMA32(kf0, qfA[dk], sa0A);
      sa1A = MFMA32(kf1, qfA[dk], sa1A);
      sa0B = MFMA32(kf0, qfB[dk], sa0B);
      sa1B = MFMA32(kf1, qfB[dk], sa1B);
    }
    __builtin_amdgcn_s_setprio(0);

    // ---- static-bound softmax, tile A then tile B
    u32 wA[2][8], wB[2][8];
    float ssA = 0.f, ssB = 0.f;
#pragma unroll
    for (int i = 0; i < 8; ++i) {
      const float p0 = fexp2(fmaf(sa0A[2 * i], SC2, NC2));
      const float p1 = fexp2(fmaf(sa0A[2 * i + 1], SC2, NC2));
      const float p2 = fexp2(fmaf(sa1A[2 * i], SC2, NC2));
      const float p3 = fexp2(fmaf(sa1A[2 * i + 1], SC2, NC2));
      ssA += (p0 + p1) + (p2 + p3);
      bf16x2 t0, t1;
      t0[0] = (bf16_t)p0; t0[1] = (bf16_t)p1;
      t1[0] = (bf16_t)p2; t1[1] = (bf16_t)p3;
      wA[0][i] = __builtin_bit_cast(u32, t0);
      wA[1][i] = __builtin_bit_cast(u32, t1);
    }
#pragma unroll
    for (int i = 0; i < 8; ++i) {
      const float p0 = fexp2(fmaf(sa0B[2 * i], SC2, NC2));
      const float p1 = fexp2(fmaf(sa0B[2 * i + 1], SC2, NC2));
      const float p2 = fexp2(fmaf(sa1B[2 * i], SC2, NC2));
      const float p3 = fexp2(fmaf(sa1B[2 * i + 1], SC2, NC2));
      ssB += (p0 + p1) + (p2 + p3);
      bf16x2 t0, t1;
      t0[0] = (bf16_t)p0; t0[1] = (bf16_t)p1;
      t1[0] = (bf16_t)p2; t1[1] = (bf16_t)p3;
      wB[0][i] = __builtin_bit_cast(u32, t0);
      wB[1][i] = __builtin_bit_cast(u32, t1);
    }
    ssA += __shfl_xor(ssA, 32);
    ssB += __shfl_xor(ssB, 32);
    lA += ssA;
    lB += ssB;

    // ---- O^T += V^T @ P, both tiles; vf reads SHARED
#pragma unroll
    for (int ks = 0; ks < 4; ++ks) {
      const int tsel = ks >> 1, k4 = (ks & 1) * 4;
      u32 a0 = wA[tsel][k4 + 0], b0 = wA[tsel][k4 + 2];
      u32 a1 = wA[tsel][k4 + 1], b1 = wA[tsel][k4 + 3];
      pl32(a0, b0);
      pl32(a1, b1);
      u32x4 fwA;
      fwA.x = a0; fwA.y = a1; fwA.z = b0; fwA.w = b1;
      const bf16x8 pfA = __builtin_bit_cast(bf16x8, fwA);
      u32 c0 = wB[tsel][k4 + 0], d0 = wB[tsel][k4 + 2];
      u32 c1 = wB[tsel][k4 + 1], d1 = wB[tsel][k4 + 3];
      pl32(c0, d0);
      pl32(c1, d1);
      u32x4 fwB;
      fwB.x = c0; fwB.y = c1; fwB.z = d0; fwB.w = d1;
      const bf16x8 pfB = __builtin_bit_cast(bf16x8, fwB);
      const int gv = ((ks << 1) | hi) ^ r7;
      __builtin_amdgcn_s_setprio(1);
#pragma unroll
      for (int db = 0; db < 4; ++db) {
        bf16x8 vf = *(const bf16x8*)&ldsV[bu][(db * 32 + l31) * 64 + gv * 8];
        otA[db] = MFMA32(vf, pfA, otA[db]);
        otB[db] = MFMA32(vf, pfB, otB[db]);
      }
      __builtin_amdgcn_s_setprio(0);
    }

    // ---- counted-vmcnt buffer rotation (never drain to 0 mid-loop)
    __builtin_amdgcn_s_barrier();
    __builtin_amdgcn_sched_barrier(0);
    if (kt < 30) {
      stage(kt + 2, bu);
      asm volatile("s_waitcnt vmcnt(4)" ::: "memory");
    } else {
      asm volatile("s_waitcnt vmcnt(0)" ::: "memory");
    }
    __builtin_amdgcn_s_barrier();
    __builtin_amdgcn_sched_barrier(0);
  }

  // ---- epilogue, both tiles
  const float rlA = 1.f / lA, rlB = 1.f / lB;
  const size_t yrA = ((size_t)(b * 2048 + q0 + l31) * 16 + h) * 128;
  const size_t yrB = ((size_t)(b * 2048 + q0 + 256 + l31) * 16 + h) * 128;
#pragma unroll
  for (int db = 0; db < 4; ++db)
#pragma unroll
    for (int g2 = 0; g2 < 4; ++g2) {
      bf16x4 ovA, ovB;
#pragma unroll
      for (int j = 0; j < 4; ++j) {
        ovA[j] = (bf16_t)(otA[db][g2 * 4 + j] * rlA);
        ovB[j] = (bf16_t)(otB[db][g2 * 4 + j] * rlB);
      }
      *(bf16x4*)&Y[yrA + db * 32 + g2 * 8 + hi * 4] = ovA;
      *(bf16x4*)&Y[yrB + db * 32 + g2 * 8 + hi * 4] = ovB;
    }
}

// ---------------------------------------------------------------------------
extern "C" void kernel_launch(void* const* d_in, const int* in_sizes, int n_in,
                              void* d_out, int out_size, void* d_ws, size_t ws_size,
                              hipStream_t stream) {
  const float* x = (const float*)d_in[0];
  const float* cs = (const float*)d_in[1];
  const float* sn = (const float*)d_in[2];
  const float* Wq = (const float*)d_in[3];
  const float* Wk = (const float*)d_in[4];
  const float* Wv = (const float*)d_in[5];
  const float* Wo = (const float*)d_in[6];

  bf16_t* ws = (bf16_t*)d_ws;
  const size_t TSZ = (size_t)4 * 2048 * 2048;
  const size_t WSZ = (size_t)2048 * 2048;
  bf16_t* xb = ws;
  bf16_t* Wqb = ws + TSZ;
  bf16_t* Wkb = Wqb + WSZ;
  bf16_t* Wvb = Wkb + WSZ;
  bf16_t* Wob = Wvb + WSZ;
  bf16_t* Qb = ws + 2 * TSZ;
  bf16_t* Kb = Qb + TSZ;
  bf16_t* Vtb = Kb + TSZ;
  bf16_t* Yb = xb;

  cvt_bf16<<<16384, 256, 0, stream>>>(x, xb);
  cvt_w4<<<16384, 256, 0, stream>>>(Wq, Wk, Wv, Wo, Wqb, Wkb, Wvb, Wob);

  gemm8<0, bf16_t, 8><<<256, 512, 0, stream>>>(xb, Wqb, Qb);
  gemm8<0, bf16_t, 8><<<256, 512, 0, stream>>>(xb, Wkb, Kb);
  gemm8<2, bf16_t, 32><<<256, 512, 0, stream>>>(Wvb, xb, Vtb);
  rope_rms2<<<8192, 256, 0, stream>>>(Qb, Kb, cs, sn);
  attn_fwd<<<256, 512, 0, stream>>>(Qb, Kb, Vtb, Yb);
  gemm8<1, float, 8><<<256, 512, 0, stream>>>(Yb, Wob, (float*)d_out);
}

// Round 11
// 502.436 us; speedup vs baseline: 1.4920x; 1.4920x over previous
//
#include <hip/hip_runtime.h>
#include <hip/hip_bf16.h>
#include <math.h>

// B=4, S=2048, E=2048, H=16, D=128. Inputs/outputs FP32; internal bf16 MFMA, f32 acc.

typedef __bf16 bf16_t;
typedef __bf16 bf16x2 __attribute__((ext_vector_type(2)));
typedef __bf16 bf16x4 __attribute__((ext_vector_type(4)));
typedef __bf16 bf16x8 __attribute__((ext_vector_type(8)));
typedef float f32x2 __attribute__((ext_vector_type(2)));
typedef float f32x4 __attribute__((ext_vector_type(4)));
typedef float f32x16 __attribute__((ext_vector_type(16)));
typedef unsigned int u32;
typedef u32 u32x4 __attribute__((ext_vector_type(4)));

typedef __attribute__((address_space(1))) const void gas_cvoid;
typedef __attribute__((address_space(3))) void las_void;

#define MFMA32(a, b, c) __builtin_amdgcn_mfma_f32_32x32x16_bf16((a), (b), (c), 0, 0, 0)

__device__ __forceinline__ void gload16(const void* g, void* l) {
  __builtin_amdgcn_global_load_lds((gas_cvoid*)g, (las_void*)l, 16, 0, 0);
}
// lane[i] <-> lane[i+32] pairwise exchange of two regs (T12 primitive, m255)
__device__ __forceinline__ void pl32(u32& a, u32& b) {
  asm volatile("v_permlane32_swap_b32 %0, %1" : "+v"(a), "+v"(b));
}
// bare v_exp_f32 (D = 2^S0); exp2f() is OCML w/ fixup, __exp2f doesn't exist.
__device__ __forceinline__ float fexp2(float x) {
  float r;
  asm("v_exp_f32 %0, %1" : "=v"(r) : "v"(x));
  return r;
}

// ---------------------------------------------------------------------------
// f32 -> bf16 elementwise, 4 elems/thread.
// ---------------------------------------------------------------------------
__global__ __launch_bounds__(256) void cvt_bf16(const float* __restrict__ in,
                                                bf16_t* __restrict__ out) {
  const size_t i = ((size_t)blockIdx.x * 256 + threadIdx.x) * 4;
  f32x4 v = *(const f32x4*)&in[i];
  bf16x4 o;
#pragma unroll
  for (int j = 0; j < 4; ++j) o[j] = (bf16_t)v[j];
  *(bf16x4*)&out[i] = o;
}
// 4 weight matrices in one launch: 4096 blocks per tensor.
__global__ __launch_bounds__(256) void cvt_w4(const float* __restrict__ w0,
                                              const float* __restrict__ w1,
                                              const float* __restrict__ w2,
                                              const float* __restrict__ w3,
                                              bf16_t* __restrict__ o0,
                                              bf16_t* __restrict__ o1,
                                              bf16_t* __restrict__ o2,
                                              bf16_t* __restrict__ o3) {
  const int which = blockIdx.x >> 12;
  const float* in = which == 0 ? w0 : which == 1 ? w1 : which == 2 ? w2 : w3;
  bf16_t* out = which == 0 ? o0 : which == 1 ? o1 : which == 2 ? o2 : o3;
  const size_t i = ((size_t)(blockIdx.x & 4095) * 256 + threadIdx.x) * 4;
  f32x4 v = *(const f32x4*)&in[i];
  bf16x4 o;
#pragma unroll
  for (int j = 0; j < 4; ++j) o[j] = (bf16_t)v[j];
  *(bf16x4*)&out[i] = o;
}

// ---------------------------------------------------------------------------
// 8-phase NT GEMM, COUNTED vmcnt, now with 32x32x16 MFMA (4061 FLOP/cyc vs
// 3378 for 16x16x32, m119; halves MFMA instruction count).
// C[M][N] = A[M][2048] @ Bt[N][2048]^T. 256x256 tile, BK=64, 512 thr / 8
// waves (2M x 4N), per-wave 128x64 = 4x2 tiles of 32x32. LDS 128 KiB dbuf.
// Fragment mapping transplanted from the HW-verified attn MFMA32 usage:
//   A-frag: row = mt*32 + l31, k-chunk = (kk*2+hi) ^ (l31&7)   [A: row=lane&31, k=hi*8+e]
//   B-frag: row(n) = nt*32 + l31, same chunk rule              [B: col=lane&31]
//   D: col = l31 (n), row m = (j&3) + 8*(j>>2) + 4*hi, j in [0,16)
// Staging order/waits unchanged (verified since round 5).
// ---------------------------------------------------------------------------
template <int MODE, typename CT, int NT_T>
__global__ __launch_bounds__(512, 2) void gemm8(const bf16_t* __restrict__ A,
                                                const bf16_t* __restrict__ Bt,
                                                CT* __restrict__ C) {
  constexpr int K = 2048;
  __shared__ __attribute__((aligned(16))) char lds[131072];
  const int tid = threadIdx.x;
  const int wave = tid >> 6, lane = tid & 63;
  const int bid = blockIdx.x;
  const int swz = (bid & 7) * 32 + (bid >> 3);  // grid 256, bijective XCD swizzle
  const int m0 = (swz / NT_T) * 256, n0 = (swz % NT_T) * 256;

  const int srow = tid >> 3;
  const int scol = ((tid & 7) ^ (srow & 7)) * 8;
  const bf16_t* aBase = A + (size_t)(m0 + srow) * K + scol;
  const bf16_t* bBase = Bt + (size_t)(n0 + srow) * K + scol;

  const int wm = wave >> 2, wn = wave & 3;
  const int l31 = lane & 31, hi = lane >> 5;
  const int axor = l31 & 7;
  char* const wdst = lds + wave * 1024;

  f32x16 acc[4][2] = {};

  // prologue: tile 0 into buf 0, canonical order
  gload16(bBase, wdst + 32768);
  gload16(bBase + (size_t)64 * K, wdst + 32768 + 8192);
  gload16(bBase + (size_t)128 * K, wdst + 32768 + 16384);
  gload16(bBase + (size_t)192 * K, wdst + 32768 + 24576);
  gload16(aBase, wdst);
  gload16(aBase + (size_t)128 * K, wdst + 16384);
  gload16(aBase + (size_t)64 * K, wdst + 8192);
  gload16(aBase + (size_t)192 * K, wdst + 24576);

  for (int t = 0; t < 32; ++t) {
    const int buf = t & 1, nbuf = buf ^ 1;
    const char* la = lds + buf * 65536 + wm * 16384;
    const char* lb = lds + buf * 65536 + 32768 + (wn >> 1) * 16384 + (wn & 1) * 8192;
    char* const ndst = wdst + nbuf * 65536;
    bf16x8 bF[2][4];
#pragma unroll
    for (int q = 0; q < 4; ++q) {
      if (q == 0) {
        asm volatile("s_waitcnt vmcnt(2)" ::: "memory");
      } else if (q == 2) {
        if (t < 31)
          asm volatile("s_waitcnt vmcnt(4)" ::: "memory");
        else
          asm volatile("s_waitcnt vmcnt(0)" ::: "memory");
      }
      __builtin_amdgcn_s_barrier();

      // A frags for m-tile q: rows q*32 + l31, k = kk*16 + hi*8
      bf16x8 aF[4];
#pragma unroll
      for (int kk = 0; kk < 4; ++kk)
        aF[kk] = *(const bf16x8*)(la + (q * 32 + l31) * 128 +
                                  ((kk * 2 + hi) ^ axor) * 16);
      if (q == 0) {
#pragma unroll
        for (int nt = 0; nt < 2; ++nt)
#pragma unroll
          for (int kk = 0; kk < 4; ++kk)
            bF[nt][kk] = *(const bf16x8*)(lb + (nt * 32 + l31) * 128 +
                                          ((kk * 2 + hi) ^ axor) * 16);
      }
      // stage tile t+1, 2 chunks per phase, canonical order
      if (t < 31) {
        const int off = (t + 1) * 64;
        if (q == 0) {
          gload16(bBase + off, ndst + 32768);
          gload16(bBase + (size_t)64 * K + off, ndst + 32768 + 8192);
        } else if (q == 1) {
          gload16(bBase + (size_t)128 * K + off, ndst + 32768 + 16384);
          gload16(bBase + (size_t)192 * K + off, ndst + 32768 + 24576);
        } else if (q == 2) {
          gload16(aBase + off, ndst);
          gload16(aBase + (size_t)128 * K + off, ndst + 16384);
        } else {
          gload16(aBase + (size_t)64 * K + off, ndst + 8192);
          gload16(aBase + (size_t)192 * K + off, ndst + 24576);
        }
      }
      __builtin_amdgcn_s_setprio(1);
#pragma unroll
      for (int kk = 0; kk < 4; ++kk)
#pragma unroll
        for (int nt = 0; nt < 2; ++nt)
          acc[q][nt] = MFMA32(aF[kk], bF[nt][kk], acc[q][nt]);
      __builtin_amdgcn_s_setprio(0);
    }
  }

  // epilogue: r = m0 + wm*128 + mt*32 + (j&3) + 8*(j>>2) + 4*hi, c = n0 + wn*64 + nt*32 + l31
  const int rBase = m0 + wm * 128 + 4 * hi;
  const int cBase = n0 + wn * 64 + l31;
#pragma unroll
  for (int mt = 0; mt < 4; ++mt)
#pragma unroll
    for (int nt = 0; nt < 2; ++nt)
#pragma unroll
      for (int j = 0; j < 16; ++j) {
        const int r = rBase + mt * 32 + (j & 3) + 8 * (j >> 2);
        const int c = cBase + nt * 32;
        const CT v = (CT)acc[mt][nt][j];
        if (MODE == 0) {
          const int b = r >> 11, s = r & 2047, hh = c >> 7, d = c & 127;
          C[(((size_t)(b * 16 + hh)) * 2048 + s) * 128 + d] = v;
        } else if (MODE == 1) {
          C[(size_t)r * 2048 + c] = v;
        } else {  // r = h*128+dd (Wv row), c = b*2048+s
          const int hh = r >> 7, dd = r & 127, b = c >> 11, s = c & 2047;
          C[((size_t)(b * 16 + hh) * 128 + dd) * 2048 + s] = v;
        }
      }
}

// ---------------------------------------------------------------------------
// Fused RoPE + RMSNorm on BOTH Q and K in one dispatch (grid 8192).
// ---------------------------------------------------------------------------
__global__ __launch_bounds__(256) void rope_rms2(bf16_t* __restrict__ Qb,
                                                 bf16_t* __restrict__ Kb,
                                                 const float* __restrict__ Cs,
                                                 const float* __restrict__ Sn) {
  bf16_t* T = (blockIdx.x >> 12) ? Kb : Qb;
  const int bid = blockIdx.x & 4095;
  const int wave = threadIdx.x >> 6, lane = threadIdx.x & 63;
#pragma unroll 1
  for (int rr = 0; rr < 8; ++rr) {
    const size_t row = (size_t)bid * 32 + wave * 8 + rr;
    const int s = (int)(row & 2047);
    bf16_t* p = &T[row * 128 + 2 * lane];
    const float a0 = (float)p[0], a1 = (float)p[1];
    f32x2 cv = *(const f32x2*)&Cs[(size_t)s * 128 + 2 * lane];
    f32x2 sv = *(const f32x2*)&Sn[(size_t)s * 128 + 2 * lane];
    const float p0 = __shfl_xor(a0, 32);
    const float p1 = __shfl_xor(a1, 32);
    const float sg = (lane < 32) ? -1.f : 1.f;
    const float r0 = a0 * cv.x + sg * p0 * sv.x;
    const float r1 = a1 * cv.y + sg * p1 * sv.y;
    float ss = r0 * r0 + r1 * r1;
#pragma unroll
    for (int off = 1; off < 64; off <<= 1) ss += __shfl_xor(ss, off);
    const float inv = rsqrtf(ss * (1.0f / 128.0f) + 1e-6f);
    p[0] = (bf16_t)(r0 * inv);
    p[1] = (bf16_t)(r1 * inv);
  }
}

// ---------------------------------------------------------------------------
// Flash attention: ROUND-9 version exactly (178 us verified; the round-10
// 2-q-tile variant spilled ~320 regs -> 1.8 GB scratch traffic, reverted).
// Static-bound softmax (Cauchy-Schwarz M=11.5 from QK-RMSNorm), counted-vmcnt
// rotation, r&7 swizzle.
// ---------------------------------------------------------------------------
__global__ __launch_bounds__(512, 2) void attn_fwd(const bf16_t* __restrict__ Q,
                                                   const bf16_t* __restrict__ K,
                                                   const bf16_t* __restrict__ Vt,
                                                   bf16_t* __restrict__ Y) {
  __shared__ __attribute__((aligned(16))) bf16_t ldsK[2][64 * 128];
  __shared__ __attribute__((aligned(16))) bf16_t ldsV[2][128 * 64];
  const int tid = threadIdx.x, wave = tid >> 6, lane = tid & 63;
  const int l31 = lane & 31, hi = lane >> 5;
  const int pid = blockIdx.x;
  const int bh = (pid & 7) * 8 + ((pid >> 3) & 7);
  const int qb = pid >> 6;
  const int b = bh >> 4, h = bh & 15;
  const bf16_t* Qh = Q + (size_t)bh * 2048 * 128;
  const bf16_t* Kh = K + (size_t)bh * 2048 * 128;
  const bf16_t* Vh = Vt + (size_t)bh * 128 * 2048;
  const int q0 = qb * 256 + wave * 32;

  bf16x8 qf[8];
#pragma unroll
  for (int dk = 0; dk < 8; ++dk)
    qf[dk] = *(const bf16x8*)&Qh[(size_t)(q0 + l31) * 128 + dk * 16 + hi * 8];

  f32x16 ot[4] = {};
  float l_r = 0.f;
  const float SC2 = 0.08838834764831845f * 1.44269504088896341f;  // scale*log2e
  const float NC2 = -11.5f * 1.44269504088896341f;                // -M*log2e

  auto stage = [&](int kt, int bu) {
#pragma unroll
    for (int i = 0; i < 2; ++i) {
      const int G = wave * 64 + lane + i * 512;
      char* dstK = (char*)&ldsK[bu][0] + (wave * 64 + i * 512) * 16;
      char* dstV = (char*)&ldsV[bu][0] + (wave * 64 + i * 512) * 16;
      const int kvr = G >> 4, glk = G & 15;
      gload16(Kh + (size_t)(kt * 64 + kvr) * 128 + ((glk ^ (kvr & 7)) * 8), dstK);
      const int dr = G >> 3, glv = G & 7;
      gload16(Vh + (size_t)dr * 2048 + kt * 64 + ((glv ^ (dr & 7)) * 8), dstV);
    }
  };

  // prologue: tiles 0 and 1 in flight; wait tile 0 only
  stage(0, 0);
  stage(1, 1);
  asm volatile("s_waitcnt vmcnt(4)" ::: "memory");
  __builtin_amdgcn_s_barrier();
  __builtin_amdgcn_sched_barrier(0);

  for (int kt = 0; kt < 32; ++kt) {
    const int bu = kt & 1;
    const int r7 = l31 & 7;

    // ---- S^T = K @ Q^T (two independent 8-deep MFMA chains)
    f32x16 sa0 = {}, sa1 = {};
    __builtin_amdgcn_s_setprio(1);
#pragma unroll
    for (int dk = 0; dk < 8; ++dk) {
      const int g = ((dk << 1) | hi) ^ r7;
      bf16x8 kf0 = *(const bf16x8*)&ldsK[bu][l31 * 128 + g * 8];
      bf16x8 kf1 = *(const bf16x8*)&ldsK[bu][(32 + l31) * 128 + g * 8];
      sa0 = MFMA32(kf0, qf[dk], sa0);
      sa1 = MFMA32(kf1, qf[dk], sa1);
    }
    __builtin_amdgcn_s_setprio(0);

    // ---- static-bound softmax: p = 2^(fma(s,SC2,NC2)); no max/rescale path
    u32 w[2][8];
    float ssum = 0.f;
#pragma unroll
    for (int i = 0; i < 8; ++i) {
      const float p0 = fexp2(fmaf(sa0[2 * i], SC2, NC2));
      const float p1 = fexp2(fmaf(sa0[2 * i + 1], SC2, NC2));
      const float p2 = fexp2(fmaf(sa1[2 * i], SC2, NC2));
      const float p3 = fexp2(fmaf(sa1[2 * i + 1], SC2, NC2));
      ssum += (p0 + p1) + (p2 + p3);
      bf16x2 t0, t1;
      t0[0] = (bf16_t)p0; t0[1] = (bf16_t)p1;
      t1[0] = (bf16_t)p2; t1[1] = (bf16_t)p3;
      w[0][i] = __builtin_bit_cast(u32, t0);
      w[1][i] = __builtin_bit_cast(u32, t1);
    }
    ssum += __shfl_xor(ssum, 32);
    l_r += ssum;

    // ---- O^T += V^T @ P (P frags via permlane32_swap)
#pragma unroll
    for (int ks = 0; ks < 4; ++ks) {
      const int tsel = ks >> 1, k4 = (ks & 1) * 4;
      u32 a0 = w[tsel][k4 + 0], b0 = w[tsel][k4 + 2];
      u32 a1 = w[tsel][k4 + 1], b1 = w[tsel][k4 + 3];
      pl32(a0, b0);
      pl32(a1, b1);
      u32x4 fw;
      fw.x = a0; fw.y = a1; fw.z = b0; fw.w = b1;
      const bf16x8 pf = __builtin_bit_cast(bf16x8, fw);
      const int gv = ((ks << 1) | hi) ^ r7;
      __builtin_amdgcn_s_setprio(1);
#pragma unroll
      for (int db = 0; db < 4; ++db) {
        bf16x8 vf = *(const bf16x8*)&ldsV[bu][(db * 32 + l31) * 64 + gv * 8];
        ot[db] = MFMA32(vf, pf, ot[db]);
      }
      __builtin_amdgcn_s_setprio(0);
    }

    // ---- counted-vmcnt buffer rotation (never drain to 0 mid-loop)
    __builtin_amdgcn_s_barrier();
    __builtin_amdgcn_sched_barrier(0);
    if (kt < 30) {
      stage(kt + 2, bu);
      asm volatile("s_waitcnt vmcnt(4)" ::: "memory");
    } else {
      asm volatile("s_waitcnt vmcnt(0)" ::: "memory");
    }
    __builtin_amdgcn_s_barrier();
    __builtin_amdgcn_sched_barrier(0);
  }

  const float rl = 1.f / l_r;
  const size_t yrow = ((size_t)(b * 2048 + q0 + l31) * 16 + h) * 128;
#pragma unroll
  for (int db = 0; db < 4; ++db)
#pragma unroll
    for (int g2 = 0; g2 < 4; ++g2) {
      bf16x4 ov;
#pragma unroll
      for (int j = 0; j < 4; ++j) ov[j] = (bf16_t)(ot[db][g2 * 4 + j] * rl);
      *(bf16x4*)&Y[yrow + db * 32 + g2 * 8 + hi * 4] = ov;
    }
}

// ---------------------------------------------------------------------------
extern "C" void kernel_launch(void* const* d_in, const int* in_sizes, int n_in,
                              void* d_out, int out_size, void* d_ws, size_t ws_size,
                              hipStream_t stream) {
  const float* x = (const float*)d_in[0];
  const float* cs = (const float*)d_in[1];
  const float* sn = (const float*)d_in[2];
  const float* Wq = (const float*)d_in[3];
  const float* Wk = (const float*)d_in[4];
  const float* Wv = (const float*)d_in[5];
  const float* Wo = (const float*)d_in[6];

  bf16_t* ws = (bf16_t*)d_ws;
  const size_t TSZ = (size_t)4 * 2048 * 2048;
  const size_t WSZ = (size_t)2048 * 2048;
  bf16_t* xb = ws;
  bf16_t* Wqb = ws + TSZ;
  bf16_t* Wkb = Wqb + WSZ;
  bf16_t* Wvb = Wkb + WSZ;
  bf16_t* Wob = Wvb + WSZ;
  bf16_t* Qb = ws + 2 * TSZ;
  bf16_t* Kb = Qb + TSZ;
  bf16_t* Vtb = Kb + TSZ;
  bf16_t* Yb = xb;

  cvt_bf16<<<16384, 256, 0, stream>>>(x, xb);
  cvt_w4<<<16384, 256, 0, stream>>>(Wq, Wk, Wv, Wo, Wqb, Wkb, Wvb, Wob);

  gemm8<0, bf16_t, 8><<<256, 512, 0, stream>>>(xb, Wqb, Qb);
  gemm8<0, bf16_t, 8><<<256, 512, 0, stream>>>(xb, Wkb, Kb);
  gemm8<2, bf16_t, 32><<<256, 512, 0, stream>>>(Wvb, xb, Vtb);
  rope_rms2<<<8192, 256, 0, stream>>>(Qb, Kb, cs, sn);
  attn_fwd<<<512, 512, 0, stream>>>(Qb, Kb, Vtb, Yb);
  gemm8<1, float, 8><<<256, 512, 0, stream>>>(Yb, Wob, (float*)d_out);
}

// Round 12
// 472.499 us; speedup vs baseline: 1.5865x; 1.0634x over previous
//
#include <hip/hip_runtime.h>
#include <hip/hip_bf16.h>
#include <math.h>

// B=4, S=2048, E=2048, H=16, D=128. Inputs/outputs FP32; internal bf16 MFMA, f32 acc.

typedef __bf16 bf16_t;
typedef __bf16 bf16x2 __attribute__((ext_vector_type(2)));
typedef __bf16 bf16x4 __attribute__((ext_vector_type(4)));
typedef __bf16 bf16x8 __attribute__((ext_vector_type(8)));
typedef float f32x2 __attribute__((ext_vector_type(2)));
typedef float f32x4 __attribute__((ext_vector_type(4)));
typedef float f32x16 __attribute__((ext_vector_type(16)));
typedef unsigned int u32;
typedef u32 u32x4 __attribute__((ext_vector_type(4)));

typedef __attribute__((address_space(1))) const void gas_cvoid;
typedef __attribute__((address_space(3))) void las_void;

#define MFMA16(a, b, c) __builtin_amdgcn_mfma_f32_16x16x32_bf16((a), (b), (c), 0, 0, 0)
#define MFMA32(a, b, c) __builtin_amdgcn_mfma_f32_32x32x16_bf16((a), (b), (c), 0, 0, 0)

__device__ __forceinline__ void gload16(const void* g, void* l) {
  __builtin_amdgcn_global_load_lds((gas_cvoid*)g, (las_void*)l, 16, 0, 0);
}
// lane[i] <-> lane[i+32] pairwise exchange of two regs (T12 primitive, m255)
__device__ __forceinline__ void pl32(u32& a, u32& b) {
  asm volatile("v_permlane32_swap_b32 %0, %1" : "+v"(a), "+v"(b));
}
// bare v_exp_f32 (D = 2^S0); exp2f() is OCML w/ fixup, __exp2f doesn't exist.
__device__ __forceinline__ float fexp2(float x) {
  float r;
  asm("v_exp_f32 %0, %1" : "=v"(r) : "v"(x));
  return r;
}

// ---------------------------------------------------------------------------
// f32 -> bf16 elementwise, 4 elems/thread.
// ---------------------------------------------------------------------------
__global__ __launch_bounds__(256) void cvt_bf16(const float* __restrict__ in,
                                                bf16_t* __restrict__ out) {
  const size_t i = ((size_t)blockIdx.x * 256 + threadIdx.x) * 4;
  f32x4 v = *(const f32x4*)&in[i];
  bf16x4 o;
#pragma unroll
  for (int j = 0; j < 4; ++j) o[j] = (bf16_t)v[j];
  *(bf16x4*)&out[i] = o;
}
// 4 weight matrices in one launch: 4096 blocks per tensor.
__global__ __launch_bounds__(256) void cvt_w4(const float* __restrict__ w0,
                                              const float* __restrict__ w1,
                                              const float* __restrict__ w2,
                                              const float* __restrict__ w3,
                                              bf16_t* __restrict__ o0,
                                              bf16_t* __restrict__ o1,
                                              bf16_t* __restrict__ o2,
                                              bf16_t* __restrict__ o3) {
  const int which = blockIdx.x >> 12;
  const float* in = which == 0 ? w0 : which == 1 ? w1 : which == 2 ? w2 : w3;
  bf16_t* out = which == 0 ? o0 : which == 1 ? o1 : which == 2 ? o2 : o3;
  const size_t i = ((size_t)(blockIdx.x & 4095) * 256 + threadIdx.x) * 4;
  f32x4 v = *(const f32x4*)&in[i];
  bf16x4 o;
#pragma unroll
  for (int j = 0; j < 4; ++j) o[j] = (bf16_t)v[j];
  *(bf16x4*)&out[i] = o;
}

// ---------------------------------------------------------------------------
// 8-phase NT GEMM with COUNTED vmcnt, 16x16x32 MFMA (round-7/9 verified best:
// ~61 us per dispatch; the MFMA32 variant regressed -- only 2 independent
// acc chains/phase -> dependency-stall-bound despite higher pipe ceiling).
// C[M][N] = A[M][2048] @ Bt[N][2048]^T. 256x256 tile, BK=64, 512 thr / 8
// waves (2M x 4N). LDS 128 KiB dbuf.
// ---------------------------------------------------------------------------
template <int MODE, typename CT, int NT_T>
__global__ __launch_bounds__(512, 2) void gemm8(const bf16_t* __restrict__ A,
                                                const bf16_t* __restrict__ Bt,
                                                CT* __restrict__ C) {
  constexpr int K = 2048;
  __shared__ __attribute__((aligned(16))) char lds[131072];
  const int tid = threadIdx.x;
  const int wave = tid >> 6, lane = tid & 63;
  const int bid = blockIdx.x;
  const int swz = (bid & 7) * 32 + (bid >> 3);  // grid 256, bijective XCD swizzle
  const int m0 = (swz / NT_T) * 256, n0 = (swz % NT_T) * 256;

  const int srow = tid >> 3;
  const int scol = ((tid & 7) ^ (srow & 7)) * 8;
  const bf16_t* aBase = A + (size_t)(m0 + srow) * K + scol;
  const bf16_t* bBase = Bt + (size_t)(n0 + srow) * K + scol;

  const int wm = wave >> 2, wn = wave & 3;
  const int l15 = lane & 15, l4 = lane >> 4;
  const int axor = l15 & 7;
  char* const wdst = lds + wave * 1024;

  f32x4 acc[8][4] = {};

  // prologue: tile 0 into buf 0, canonical order
  gload16(bBase, wdst + 32768);
  gload16(bBase + (size_t)64 * K, wdst + 32768 + 8192);
  gload16(bBase + (size_t)128 * K, wdst + 32768 + 16384);
  gload16(bBase + (size_t)192 * K, wdst + 32768 + 24576);
  gload16(aBase, wdst);
  gload16(aBase + (size_t)128 * K, wdst + 16384);
  gload16(aBase + (size_t)64 * K, wdst + 8192);
  gload16(aBase + (size_t)192 * K, wdst + 24576);

  for (int t = 0; t < 32; ++t) {
    const int buf = t & 1, nbuf = buf ^ 1;
    const char* la = lds + buf * 65536 + wm * 16384;
    const char* lb = lds + buf * 65536 + 32768 + (wn >> 1) * 16384 + (wn & 1) * 8192;
    char* const ndst = wdst + nbuf * 65536;
    bf16x8 bF[4][2];
#pragma unroll
    for (int q = 0; q < 4; ++q) {
      if (q == 0) {
        asm volatile("s_waitcnt vmcnt(2)" ::: "memory");
      } else if (q == 2) {
        if (t < 31)
          asm volatile("s_waitcnt vmcnt(4)" ::: "memory");
        else
          asm volatile("s_waitcnt vmcnt(0)" ::: "memory");
      }
      __builtin_amdgcn_s_barrier();

      bf16x8 aF[2][2];
#pragma unroll
      for (int dm = 0; dm < 2; ++dm)
#pragma unroll
        for (int kk = 0; kk < 2; ++kk)
          aF[dm][kk] = *(const bf16x8*)(la + ((q * 2 + dm) * 16 + l15) * 128 +
                                        ((kk * 4 + l4) ^ axor) * 16);
      if (q == 0) {
#pragma unroll
        for (int ni = 0; ni < 4; ++ni)
#pragma unroll
          for (int kk = 0; kk < 2; ++kk)
            bF[ni][kk] = *(const bf16x8*)(lb + (ni * 16 + l15) * 128 +
                                          ((kk * 4 + l4) ^ axor) * 16);
      }
      // stage tile t+1, 2 chunks per phase, canonical order
      if (t < 31) {
        const int off = (t + 1) * 64;
        if (q == 0) {
          gload16(bBase + off, ndst + 32768);
          gload16(bBase + (size_t)64 * K + off, ndst + 32768 + 8192);
        } else if (q == 1) {
          gload16(bBase + (size_t)128 * K + off, ndst + 32768 + 16384);
          gload16(bBase + (size_t)192 * K + off, ndst + 32768 + 24576);
        } else if (q == 2) {
          gload16(aBase + off, ndst);
          gload16(aBase + (size_t)128 * K + off, ndst + 16384);
        } else {
          gload16(aBase + (size_t)64 * K + off, ndst + 8192);
          gload16(aBase + (size_t)192 * K + off, ndst + 24576);
        }
      }
      __builtin_amdgcn_s_setprio(1);
#pragma unroll
      for (int kk = 0; kk < 2; ++kk)
#pragma unroll
        for (int dm = 0; dm < 2; ++dm)
#pragma unroll
          for (int ni = 0; ni < 4; ++ni)
            acc[q * 2 + dm][ni] = MFMA16(aF[dm][kk], bF[ni][kk], acc[q * 2 + dm][ni]);
      __builtin_amdgcn_s_setprio(0);
    }
  }

  const int rBase = m0 + wm * 128 + l4 * 4;
  const int cBase = n0 + wn * 64 + l15;
#pragma unroll
  for (int mi = 0; mi < 8; ++mi)
#pragma unroll
    for (int ni = 0; ni < 4; ++ni)
#pragma unroll
      for (int j = 0; j < 4; ++j) {
        const int r = rBase + mi * 16 + j;
        const int c = cBase + ni * 16;
        const CT v = (CT)acc[mi][ni][j];
        if (MODE == 0) {
          const int b = r >> 11, s = r & 2047, hh = c >> 7, d = c & 127;
          C[(((size_t)(b * 16 + hh)) * 2048 + s) * 128 + d] = v;
        } else if (MODE == 1) {
          C[(size_t)r * 2048 + c] = v;
        } else {  // r = h*128+dd (Wv row), c = b*2048+s
          const int hh = r >> 7, dd = r & 127, b = c >> 11, s = c & 2047;
          C[((size_t)(b * 16 + hh) * 128 + dd) * 2048 + s] = v;
        }
      }
}

// ---------------------------------------------------------------------------
// Fused RoPE + RMSNorm on BOTH Q and K in one dispatch (grid 8192).
// ---------------------------------------------------------------------------
__global__ __launch_bounds__(256) void rope_rms2(bf16_t* __restrict__ Qb,
                                                 bf16_t* __restrict__ Kb,
                                                 const float* __restrict__ Cs,
                                                 const float* __restrict__ Sn) {
  bf16_t* T = (blockIdx.x >> 12) ? Kb : Qb;
  const int bid = blockIdx.x & 4095;
  const int wave = threadIdx.x >> 6, lane = threadIdx.x & 63;
#pragma unroll 1
  for (int rr = 0; rr < 8; ++rr) {
    const size_t row = (size_t)bid * 32 + wave * 8 + rr;
    const int s = (int)(row & 2047);
    bf16_t* p = &T[row * 128 + 2 * lane];
    const float a0 = (float)p[0], a1 = (float)p[1];
    f32x2 cv = *(const f32x2*)&Cs[(size_t)s * 128 + 2 * lane];
    f32x2 sv = *(const f32x2*)&Sn[(size_t)s * 128 + 2 * lane];
    const float p0 = __shfl_xor(a0, 32);
    const float p1 = __shfl_xor(a1, 32);
    const float sg = (lane < 32) ? -1.f : 1.f;
    const float r0 = a0 * cv.x + sg * p0 * sv.x;
    const float r1 = a1 * cv.y + sg * p1 * sv.y;
    float ss = r0 * r0 + r1 * r1;
#pragma unroll
    for (int off = 1; off < 64; off <<= 1) ss += __shfl_xor(ss, off);
    const float inv = rsqrtf(ss * (1.0f / 128.0f) + 1e-6f);
    p[0] = (bf16_t)(r0 * inv);
    p[1] = (bf16_t)(r1 * inv);
  }
}

// ---------------------------------------------------------------------------
// Flash attention: ROUND-9 version exactly (178 us verified).
// Static-bound softmax (Cauchy-Schwarz M=11.5 from QK-RMSNorm), counted-vmcnt
// rotation, r&7 swizzle, permlane32 P-exchange, setprio MFMA clusters.
// ---------------------------------------------------------------------------
__global__ __launch_bounds__(512, 2) void attn_fwd(const bf16_t* __restrict__ Q,
                                                   const bf16_t* __restrict__ K,
                                                   const bf16_t* __restrict__ Vt,
                                                   bf16_t* __restrict__ Y) {
  __shared__ __attribute__((aligned(16))) bf16_t ldsK[2][64 * 128];
  __shared__ __attribute__((aligned(16))) bf16_t ldsV[2][128 * 64];
  const int tid = threadIdx.x, wave = tid >> 6, lane = tid & 63;
  const int l31 = lane & 31, hi = lane >> 5;
  const int pid = blockIdx.x;
  const int bh = (pid & 7) * 8 + ((pid >> 3) & 7);
  const int qb = pid >> 6;
  const int b = bh >> 4, h = bh & 15;
  const bf16_t* Qh = Q + (size_t)bh * 2048 * 128;
  const bf16_t* Kh = K + (size_t)bh * 2048 * 128;
  const bf16_t* Vh = Vt + (size_t)bh * 128 * 2048;
  const int q0 = qb * 256 + wave * 32;

  bf16x8 qf[8];
#pragma unroll
  for (int dk = 0; dk < 8; ++dk)
    qf[dk] = *(const bf16x8*)&Qh[(size_t)(q0 + l31) * 128 + dk * 16 + hi * 8];

  f32x16 ot[4] = {};
  float l_r = 0.f;
  const float SC2 = 0.08838834764831845f * 1.44269504088896341f;  // scale*log2e
  const float NC2 = -11.5f * 1.44269504088896341f;                // -M*log2e

  auto stage = [&](int kt, int bu) {
#pragma unroll
    for (int i = 0; i < 2; ++i) {
      const int G = wave * 64 + lane + i * 512;
      char* dstK = (char*)&ldsK[bu][0] + (wave * 64 + i * 512) * 16;
      char* dstV = (char*)&ldsV[bu][0] + (wave * 64 + i * 512) * 16;
      const int kvr = G >> 4, glk = G & 15;
      gload16(Kh + (size_t)(kt * 64 + kvr) * 128 + ((glk ^ (kvr & 7)) * 8), dstK);
      const int dr = G >> 3, glv = G & 7;
      gload16(Vh + (size_t)dr * 2048 + kt * 64 + ((glv ^ (dr & 7)) * 8), dstV);
    }
  };

  // prologue: tiles 0 and 1 in flight; wait tile 0 only
  stage(0, 0);
  stage(1, 1);
  asm volatile("s_waitcnt vmcnt(4)" ::: "memory");
  __builtin_amdgcn_s_barrier();
  __builtin_amdgcn_sched_barrier(0);

  for (int kt = 0; kt < 32; ++kt) {
    const int bu = kt & 1;
    const int r7 = l31 & 7;

    // ---- S^T = K @ Q^T (two independent 8-deep MFMA chains)
    f32x16 sa0 = {}, sa1 = {};
    __builtin_amdgcn_s_setprio(1);
#pragma unroll
    for (int dk = 0; dk < 8; ++dk) {
      const int g = ((dk << 1) | hi) ^ r7;
      bf16x8 kf0 = *(const bf16x8*)&ldsK[bu][l31 * 128 + g * 8];
      bf16x8 kf1 = *(const bf16x8*)&ldsK[bu][(32 + l31) * 128 + g * 8];
      sa0 = MFMA32(kf0, qf[dk], sa0);
      sa1 = MFMA32(kf1, qf[dk], sa1);
    }
    __builtin_amdgcn_s_setprio(0);

    // ---- static-bound softmax: p = 2^(fma(s,SC2,NC2)); no max/rescale path
    u32 w[2][8];
    float ssum = 0.f;
#pragma unroll
    for (int i = 0; i < 8; ++i) {
      const float p0 = fexp2(fmaf(sa0[2 * i], SC2, NC2));
      const float p1 = fexp2(fmaf(sa0[2 * i + 1], SC2, NC2));
      const float p2 = fexp2(fmaf(sa1[2 * i], SC2, NC2));
      const float p3 = fexp2(fmaf(sa1[2 * i + 1], SC2, NC2));
      ssum += (p0 + p1) + (p2 + p3);
      bf16x2 t0, t1;
      t0[0] = (bf16_t)p0; t0[1] = (bf16_t)p1;
      t1[0] = (bf16_t)p2; t1[1] = (bf16_t)p3;
      w[0][i] = __builtin_bit_cast(u32, t0);
      w[1][i] = __builtin_bit_cast(u32, t1);
    }
    ssum += __shfl_xor(ssum, 32);
    l_r += ssum;

    // ---- O^T += V^T @ P (P frags via permlane32_swap)
#pragma unroll
    for (int ks = 0; ks < 4; ++ks) {
      const int tsel = ks >> 1, k4 = (ks & 1) * 4;
      u32 a0 = w[tsel][k4 + 0], b0 = w[tsel][k4 + 2];
      u32 a1 = w[tsel][k4 + 1], b1 = w[tsel][k4 + 3];
      pl32(a0, b0);
      pl32(a1, b1);
      u32x4 fw;
      fw.x = a0; fw.y = a1; fw.z = b0; fw.w = b1;
      const bf16x8 pf = __builtin_bit_cast(bf16x8, fw);
      const int gv = ((ks << 1) | hi) ^ r7;
      __builtin_amdgcn_s_setprio(1);
#pragma unroll
      for (int db = 0; db < 4; ++db) {
        bf16x8 vf = *(const bf16x8*)&ldsV[bu][(db * 32 + l31) * 64 + gv * 8];
        ot[db] = MFMA32(vf, pf, ot[db]);
      }
      __builtin_amdgcn_s_setprio(0);
    }

    // ---- counted-vmcnt buffer rotation (never drain to 0 mid-loop)
    __builtin_amdgcn_s_barrier();
    __builtin_amdgcn_sched_barrier(0);
    if (kt < 30) {
      stage(kt + 2, bu);
      asm volatile("s_waitcnt vmcnt(4)" ::: "memory");
    } else {
      asm volatile("s_waitcnt vmcnt(0)" ::: "memory");
    }
    __builtin_amdgcn_s_barrier();
    __builtin_amdgcn_sched_barrier(0);
  }

  const float rl = 1.f / l_r;
  const size_t yrow = ((size_t)(b * 2048 + q0 + l31) * 16 + h) * 128;
#pragma unroll
  for (int db = 0; db < 4; ++db)
#pragma unroll
    for (int g2 = 0; g2 < 4; ++g2) {
      bf16x4 ov;
#pragma unroll
      for (int j = 0; j < 4; ++j) ov[j] = (bf16_t)(ot[db][g2 * 4 + j] * rl);
      *(bf16x4*)&Y[yrow + db * 32 + g2 * 8 + hi * 4] = ov;
    }
}

// ---------------------------------------------------------------------------
extern "C" void kernel_launch(void* const* d_in, const int* in_sizes, int n_in,
                              void* d_out, int out_size, void* d_ws, size_t ws_size,
                              hipStream_t stream) {
  const float* x = (const float*)d_in[0];
  const float* cs = (const float*)d_in[1];
  const float* sn = (const float*)d_in[2];
  const float* Wq = (const float*)d_in[3];
  const float* Wk = (const float*)d_in[4];
  const float* Wv = (const float*)d_in[5];
  const float* Wo = (const float*)d_in[6];

  bf16_t* ws = (bf16_t*)d_ws;
  const size_t TSZ = (size_t)4 * 2048 * 2048;
  const size_t WSZ = (size_t)2048 * 2048;
  bf16_t* xb = ws;
  bf16_t* Wqb = ws + TSZ;
  bf16_t* Wkb = Wqb + WSZ;
  bf16_t* Wvb = Wkb + WSZ;
  bf16_t* Wob = Wvb + WSZ;
  bf16_t* Qb = ws + 2 * TSZ;
  bf16_t* Kb = Qb + TSZ;
  bf16_t* Vtb = Kb + TSZ;
  bf16_t* Yb = xb;

  cvt_bf16<<<16384, 256, 0, stream>>>(x, xb);
  cvt_w4<<<16384, 256, 0, stream>>>(Wq, Wk, Wv, Wo, Wqb, Wkb, Wvb, Wob);

  gemm8<0, bf16_t, 8><<<256, 512, 0, stream>>>(xb, Wqb, Qb);
  gemm8<0, bf16_t, 8><<<256, 512, 0, stream>>>(xb, Wkb, Kb);
  gemm8<2, bf16_t, 32><<<256, 512, 0, stream>>>(Wvb, xb, Vtb);
  rope_rms2<<<8192, 256, 0, stream>>>(Qb, Kb, cs, sn);
  attn_fwd<<<512, 512, 0, stream>>>(Qb, Kb, Vtb, Yb);
  gemm8<1, float, 8><<<256, 512, 0, stream>>>(Yb, Wob, (float*)d_out);
}